// Round 15
// baseline (23.052 us; speedup 1.0000x reference)
//
#include <hip/hip_runtime.h>
#include <hip/hip_fp16.h>

// B=32, L=512, N=128, IN=16, OUT=10
// Three kernels (fence-free skeleton + XCD affinity):
//  K1 k_micro   : 256 blocks x 64 rows; W1/W2 columns in registers reused
//                 across 8 row-passes; ballot-builds mask_tab[4][512] (node
//                 bitmasks per leaf) for K2; block 0 zeroes yfix.
//  K2 k_agg_part: same-XCD readers; f16 bitmask max-agg (mask via 1 coalesced
//                 load) + f_macro + W4 slice; Q32.32 atomicAdd into yfix.
//  K3 k_bn_out  : yfix -> y=relu(.+b4); BatchNorm (batch stats); @W5+b5.

static __device__ __forceinline__ unsigned pk_max_f16(unsigned a, unsigned b) {
    unsigned r;
    asm("v_pk_max_f16 %0, %1, %2" : "=v"(r) : "v"(a), "v"(b));
    return r;
}

__global__ __launch_bounds__(256) void k_micro(
    const float* __restrict__ x, const float* __restrict__ tree,
    const float* __restrict__ W1, const float* __restrict__ b1,
    const float* __restrict__ W2, const float* __restrict__ b2,
    unsigned* __restrict__ h16, unsigned* __restrict__ mask_tab,
    unsigned long long* __restrict__ yfix)
{
    const int gid = blockIdx.x;             // 0..255
    const int xcd = gid & 7;
    const int t   = gid >> 3;               // 0..31
    const int bq  = t >> 3;                 // 0..3
    const int rb  = t & 7;                  // 0..7
    const int b   = bq * 8 + xcd;           // batch pinned to XCD b%8
    const int row0 = b * 512 + rb * 64;     // 64 rows per block

    const int tid = threadIdx.x;
    const int r = tid >> 5;                 // row-in-pass (0..7)
    const int p = tid & 31;                 // channel pair / layer1 col

    if (gid == 0) {                         // reset Q32.32 accumulators
        #pragma unroll
        for (int i = tid; i < 2048; i += 256) yfix[i] = 0ull;
    }

    __shared__ float sx[64][16];            // 4 KB
    __shared__ float sh1[64][32];           // 8 KB

    // stage x for 64 rows (1024 floats, 4 per thread, coalesced)
    #pragma unroll
    for (int i = 0; i < 4; ++i)
        ((float*)sx)[tid + 256 * i] = x[(size_t)row0 * 16 + tid + 256 * i];

    // ---- ballot-build 8 words of the node-bitmask table ----
    // mask_tab[w*512 + leaf] bit k = (tree[w*32+k][leaf] > 0.5)
    {
        const int wv  = tid >> 6, l = tid & 63;
        const int idx = gid * 8 + wv * 2 + (l >> 5);   // 0..2047
        const int w   = idx >> 9, leaf = idx & 511;
        const bool pred = tree[(size_t)(w * 32 + (l & 31)) * 512 + leaf] > 0.5f;
        const unsigned long long m = __ballot(pred);
        if ((l & 31) == 0)
            mask_tab[idx] = (unsigned)(m >> ((l >> 5) * 32));
    }

    // weight columns in registers, reused across 8 passes
    float w1c[16];
    #pragma unroll
    for (int i = 0; i < 16; ++i) w1c[i] = W1[i * 32 + p];
    float2 w2[32];
    #pragma unroll
    for (int j = 0; j < 32; ++j) w2[j] = *(const float2*)&W2[j * 64 + 2 * p];
    const float  b1c = b1[p];
    const float2 b2p = *(const float2*)&b2[2 * p];
    __syncthreads();

    // layer1: 8 passes x (8 rows x 32 cols)
    #pragma unroll
    for (int q = 0; q < 8; ++q) {
        const int row = q * 8 + r;
        float a = b1c;
        #pragma unroll
        for (int i = 0; i < 16; ++i) a += sx[row][i] * w1c[i];
        sh1[row][p] = fmaxf(a, 0.f);
    }
    __syncthreads();

    // layer2: 8 passes, 2 channels/thread, pack f16x2
    #pragma unroll
    for (int q = 0; q < 8; ++q) {
        const int row = q * 8 + r;
        float a0 = b2p.x, a1 = b2p.y;
        #pragma unroll
        for (int j = 0; j < 32; ++j) {
            const float v = sh1[row][j];
            a0 += v * w2[j].x;
            a1 += v * w2[j].y;
        }
        __half2 hp = __floats2half2_rn(fmaxf(a0, 0.f), fmaxf(a1, 0.f));
        h16[(size_t)(row0 + row) * 32 + p] = *(unsigned*)&hp;
    }
}

// grid 512, 512 threads = 8 waves. Readers of batch b pinned to XCD b%8.
__global__ __launch_bounds__(512, 4) void k_agg_part(
    const unsigned* __restrict__ h16,      // [B][512][32] f16x2
    const unsigned* __restrict__ mask_tab, // [4][512] node bitmasks
    const float* __restrict__ W3, const float* __restrict__ b3,
    const float* __restrict__ W4,
    unsigned long long* __restrict__ yfix)
{
    const int id   = blockIdx.x;          // 0..511
    const int xcd  = id & 7;
    const int ng   = (id >> 3) & 15;      // nodes ng*8 .. ng*8+7
    const int bq   = id >> 7;             // 0..3
    const int b    = bq * 8 + xcd;        // same XCD as K1's writers of b
    const int tid  = threadIdx.x;
    const int w    = tid >> 6;            // wave 0..7
    const int lane = tid & 63;
    const int g2   = lane >> 4;           // leaf-group 0..3
    const int p2   = lane & 15;           // pair-pair (channels 4*p2..4*p2+3)

    __shared__ unsigned smask[512];
    __shared__ float sred[8][8][64];
    __shared__ float sagg[8][64];
    __shared__ float sm[128];
    __shared__ float spart[8][64];

    // ---- per-leaf 8-bit masks: ONE coalesced load + shift ----
    smask[tid] = (mask_tab[(ng >> 2) * 512 + tid] >> ((ng & 3) * 8)) & 0xffu;
    __syncthreads();

    // ---- packed max-agg, dwordx2 loads: wave w owns leaves w*64..+63 ----
    unsigned accL[8], accH[8];
    #pragma unroll
    for (int n = 0; n < 8; ++n) { accL[n] = 0u; accH[n] = 0u; }  // h>=0 exact

    const uint2* hb = (const uint2*)(h16 + (size_t)b * 16384
                                     + (size_t)(w * 64 + g2) * 32 + 2 * p2);
    const unsigned* mp = &smask[w * 64 + g2];
    #pragma unroll 16
    for (int j = 0; j < 16; ++j) {
        const uint2 hv = hb[(size_t)j * 64];     // 4 f16 ch (8B, local L2)
        const unsigned mb = mp[4 * j];           // LDS b32 broadcast
        #pragma unroll
        for (int n = 0; n < 8; ++n) {
            const int sel = (int)(mb << (31 - n)) >> 31;   // bit n -> 0 / ~0
            accL[n] = pk_max_f16(accL[n], hv.x & (unsigned)sel);
            accH[n] = pk_max_f16(accH[n], hv.y & (unsigned)sel);
        }
    }
    // combine the 4 leaf-groups (lanes differing in bits 4,5)
    #pragma unroll
    for (int n = 0; n < 8; ++n) {
        accL[n] = pk_max_f16(accL[n], (unsigned)__shfl_xor((int)accL[n], 16));
        accH[n] = pk_max_f16(accH[n], (unsigned)__shfl_xor((int)accH[n], 16));
        accL[n] = pk_max_f16(accL[n], (unsigned)__shfl_xor((int)accL[n], 32));
        accH[n] = pk_max_f16(accH[n], (unsigned)__shfl_xor((int)accH[n], 32));
    }
    if (g2 == 0) {
        #pragma unroll
        for (int n = 0; n < 8; ++n) {
            const __half2 lo = *(const __half2*)&accL[n];
            const __half2 hi = *(const __half2*)&accH[n];
            *(float2*)&sred[w][n][4 * p2] =
                make_float2(__low2float(lo), __high2float(lo));
            *(float2*)&sred[w][n][4 * p2 + 2] =
                make_float2(__low2float(hi), __high2float(hi));
        }
    }
    __syncthreads();

    {   // combine 8 waves: tid covers (n=tid>>6, c=tid&63)
        const int n = tid >> 6, c = tid & 63;
        float v = sred[0][n][c];
        #pragma unroll
        for (int ww = 1; ww < 8; ++ww) v = fmaxf(v, sred[ww][n][c]);
        sagg[n][c] = v;
    }
    __syncthreads();

    // ---- f_macro ----
    if (tid < 128) {
        const int n = tid >> 4, jj = tid & 15;
        float a = b3[jj];
        #pragma unroll
        for (int c2 = 0; c2 < 64; ++c2)
            a += sagg[n][c2] * W3[c2 * 16 + jj];
        sm[tid] = fmaxf(a, 0.f);
    }
    __syncthreads();

    // ---- W4 slice ----
    {
        float a = 0.f;
        const float* w4p = W4 + (size_t)(ng * 128 + w * 16) * 64 + lane;
        #pragma unroll
        for (int k2 = 0; k2 < 16; ++k2)
            a += sm[w * 16 + k2] * w4p[(size_t)k2 * 64];
        spart[w][lane] = a;
    }
    __syncthreads();
    if (tid < 64) {
        float v = 0.f;
        #pragma unroll
        for (int ww = 0; ww < 8; ++ww) v += spart[ww][tid];
        // Q32.32: integer add is associative -> deterministic
        const long long q = llrintf(v * 4294967296.0f);
        atomicAdd(&yfix[(size_t)b * 64 + tid], (unsigned long long)q);
    }
}

// yfix -> y = relu(.+b4); BatchNorm (batch stats over B=32); @W5+b5.
__global__ __launch_bounds__(1024) void k_bn_out(
    const unsigned long long* __restrict__ yfix, const float* __restrict__ b4,
    const float* __restrict__ gamma, const float* __restrict__ beta,
    const float* __restrict__ W5, const float* __restrict__ b5,
    float* __restrict__ out)
{
    const int tid = threadIdx.x;
    __shared__ float sy[32 * 64];
    __shared__ float smean[64], sscale[64], sbeta[64];

    #pragma unroll
    for (int idx = tid; idx < 2048; idx += 1024) {
        const long long v = (long long)yfix[idx];
        sy[idx] = fmaxf((float)v * (1.0f / 4294967296.0f) + b4[idx & 63], 0.f);
    }
    __syncthreads();
    if (tid < 64) {
        float s1 = 0.f, s2 = 0.f;
        #pragma unroll
        for (int b = 0; b < 32; ++b) {
            const float v = sy[b * 64 + tid];
            s1 += v; s2 += v * v;
        }
        const float mean = s1 * (1.f / 32.f);
        const float var  = s2 * (1.f / 32.f) - mean * mean;  // biased, torch BN
        smean[tid]  = mean;
        sscale[tid] = gamma[tid] * rsqrtf(var + 1e-5f);
        sbeta[tid]  = beta[tid];
    }
    __syncthreads();
    if (tid < 320) {
        const int b = tid / 10, q = tid % 10;
        float acc = b5[q];
        #pragma unroll
        for (int o = 0; o < 64; ++o)
            acc += ((sy[b * 64 + o] - smean[o]) * sscale[o] + sbeta[o])
                   * W5[o * 10 + q];
        out[b * 10 + q] = acc;
    }
}

extern "C" void kernel_launch(void* const* d_in, const int* in_sizes, int n_in,
                              void* d_out, int out_size, void* d_ws, size_t ws_size,
                              hipStream_t stream) {
    const float* x     = (const float*)d_in[0];
    const float* tree  = (const float*)d_in[1];
    const float* W1    = (const float*)d_in[2];
    const float* b1    = (const float*)d_in[3];
    const float* W2    = (const float*)d_in[4];
    const float* b2    = (const float*)d_in[5];
    const float* W3    = (const float*)d_in[6];
    const float* b3    = (const float*)d_in[7];
    const float* W4    = (const float*)d_in[8];
    const float* b4    = (const float*)d_in[9];
    const float* gamma = (const float*)d_in[10];
    const float* beta  = (const float*)d_in[11];
    const float* W5    = (const float*)d_in[12];
    const float* b5    = (const float*)d_in[13];
    float* out = (float*)d_out;

    unsigned*           h16      = (unsigned*)d_ws;                         // 2 MB
    unsigned long long* yfix     = (unsigned long long*)(h16 + 16384 * 32); // 16 KB
    unsigned*           mask_tab = (unsigned*)(yfix + 2048);                // 8 KB

    k_micro   <<<256,  256, 0, stream>>>(x, tree, W1, b1, W2, b2,
                                         h16, mask_tab, yfix);
    k_agg_part<<<512,  512, 0, stream>>>(h16, mask_tab, W3, b3, W4, yfix);
    k_bn_out  <<<1,   1024, 0, stream>>>(yfix, b4, gamma, beta, W5, b5, out);
}